// Round 3
// baseline (44.813 us; speedup 1.0000x reference)
//
#include <hip/hip_runtime.h>

#define N  2048
#define K  8
#define NK 1024
#define TAU_C 0.5f
#define TAU_S 0.5f

// posT[x*K + k] = position of node x in client k's sorted index list, or -1.
// One thread per (x,k) cell; binary search => every cell written exactly once,
// no memset / init pass needed (graph contains only kernel nodes).
__global__ void fia_build_pos(const int* __restrict__ idx, int* __restrict__ posT) {
    int t = blockIdx.x * blockDim.x + threadIdx.x;   // t = x*K + k
    if (t < N * K) {
        int x = t >> 3;         // t / K
        int k = t & 7;          // t % K
        const int* a = idx + k * NK;                 // sorted, 1024 ints (L2-hot)
        int lo = 0, hi = NK;                         // search [lo, hi)
        #pragma unroll 1
        while (lo < hi) {
            int mid = (lo + hi) >> 1;
            if (a[mid] < x) lo = mid + 1; else hi = mid;
        }
        int p = (lo < NK && a[lo] == x) ? lo : -1;
        posT[t] = p;                                 // fully coalesced write
    }
}

__global__ void __launch_bounds__(256)
fia_main(const float* __restrict__ adj,
         const int* __restrict__ posT,
         float* __restrict__ out) {
    const int x  = blockIdx.y;                                   // row (block-uniform)
    const int t  = blockIdx.x * blockDim.x + threadIdx.x;
    const int y0 = t * 4;                                        // 4 consecutive columns

    // Row positions: force VECTOR loads (volatile defeats s_load/K$-cache), then
    // readfirstlane -> SGPR so the per-k skip branch is scalar.
    int ix[K];
    {
        volatile const int* pv = posT + (size_t)x * K;
        #pragma unroll
        for (int k = 0; k < K; ++k) {
            int v = pv[k];
            ix[k] = __builtin_amdgcn_readfirstlane(v);
        }
    }

    // Column positions: 4 y * 8 k = 32 contiguous ints = 8x int4 (per-lane vector).
    int jv[4 * K];
    {
        const int4* pp = (const int4*)(posT + (size_t)y0 * K);
        #pragma unroll
        for (int q = 0; q < 8; ++q) {
            int4 v = pp[q];
            jv[4 * q + 0] = v.x; jv[4 * q + 1] = v.y;
            jv[4 * q + 2] = v.z; jv[4 * q + 3] = v.w;
        }
    }

    float vals[4][K];
    float sum[4] = {0.f, 0.f, 0.f, 0.f};
    float cnt[4] = {0.f, 0.f, 0.f, 0.f};
    int   mb[4]  = {0, 0, 0, 0};

    // Pass 1: gather + sum/count. Scalar branch skips clients without row x.
    #pragma unroll
    for (int k = 0; k < K; ++k) {
        const int i = ix[k];
        #pragma unroll
        for (int yy = 0; yy < 4; ++yy) vals[yy][k] = 0.f;
        if (i >= 0) {                                            // scalar (SGPR) branch
            const float* __restrict__ bk =
                adj + ((size_t)k * NK + (size_t)i) * NK;
            #pragma unroll
            for (int yy = 0; yy < 4; ++yy) {
                int j = jv[yy * K + k];
                if (j >= 0) {                                    // exec-masked
                    float a = bk[j];
                    vals[yy][k] = a;
                    sum[yy] += a;                                // skipping +0.0f is exact
                    cnt[yy] += 1.f;
                    mb[yy]  |= 1 << k;
                }
            }
        }
    }

    // Pass 2: exact f32 rounding sequence of the reference.
    float res[4];
    #pragma unroll
    for (int yy = 0; yy < 4; ++yy) {
        float n    = fmaxf(cnt[yy], 1e-5f);
        float mean = sum[yy] / n;                                // IEEE divide
        float cs = 0.f, vs = 0.f;
        #pragma unroll
        for (int k = 0; k < K; ++k) {
            if (ix[k] >= 0) {
                bool  p = (mb[yy] >> k) & 1;
                float a = vals[yy][k];
                cs += (p && (a > TAU_C)) ? 1.f : 0.f;
                float d = a - mean;
                vs += p ? d * d : 0.f;
            }
        }
        float C = cs / n;
        float V = vs / n;
        float S = C * expf(-V);                                  // precise expf
        float r = (S > TAU_S) ? mean : 0.f;
        res[yy] = (cnt[yy] > 0.f) ? r : 0.f;
    }

    float4 o;
    o.x = res[0]; o.y = res[1]; o.z = res[2]; o.w = res[3];
    *(float4*)(out + (size_t)x * N + y0) = o;
}

extern "C" void kernel_launch(void* const* d_in, const int* in_sizes, int n_in,
                              void* d_out, int out_size, void* d_ws, size_t ws_size,
                              hipStream_t stream) {
    const float* adj  = (const float*)d_in[0];   // (K, NK, NK) f32
    const int*   idx  = (const int*)d_in[1];     // (K, NK) i32
    float*       out  = (float*)d_out;           // (N, N) f32
    int*         posT = (int*)d_ws;              // N*K ints = 64 KB

    {
        int total = N * K;                       // 16384
        int block = 256;
        int grid  = (total + block - 1) / block;
        fia_build_pos<<<grid, block, 0, stream>>>(idx, posT);
    }
    {
        dim3 block(256, 1, 1);
        dim3 grid(N / (256 * 4), N, 1);          // 2 x 2048 blocks
        fia_main<<<grid, block, 0, stream>>>(adj, posT, out);
    }
}

// Round 4
// 42.822 us; speedup vs baseline: 1.0465x; 1.0465x over previous
//
#include <hip/hip_runtime.h>

#define N  2048
#define K  8
#define NK 1024
#define TAU_C 0.5f
#define TAU_S 0.5f

// posT[x*K + k] = position of node x in client k's sorted index list, or -1.
// One thread per (x,k) cell; binary search => every cell written exactly once,
// no memset / init pass needed (graph contains only kernel nodes).
__global__ void fia_build_pos(const int* __restrict__ idx, int* __restrict__ posT) {
    int t = blockIdx.x * blockDim.x + threadIdx.x;   // t = x*K + k
    if (t < N * K) {
        int x = t >> 3;         // t / K
        int k = t & 7;          // t % K
        const int* a = idx + k * NK;                 // sorted, 1024 ints (L2-hot)
        int lo = 0, hi = NK;                         // search [lo, hi)
        #pragma unroll 1
        while (lo < hi) {
            int mid = (lo + hi) >> 1;
            if (a[mid] < x) lo = mid + 1; else hi = mid;
        }
        int p = (lo < NK && a[lo] == x) ? lo : -1;
        posT[t] = p;                                 // fully coalesced write
    }
}

__global__ void __launch_bounds__(256)
fia_main(const float* __restrict__ adj,
         const int* __restrict__ posT,
         float* __restrict__ out) {
    const int x  = blockIdx.y;                                   // row (block-uniform)
    const int t  = blockIdx.x * blockDim.x + threadIdx.x;
    const int y0 = t * 4;                                        // 4 consecutive columns

    // Row positions: ONE lane-varying vector load (lanes 0..7 carry k=0..7),
    // then readlane -> wave-uniform SGPRs. Lane-varying address guarantees a
    // global_load (not s_load), which graph replay handles correctly (R3).
    int myix = posT[(size_t)x * K + (threadIdx.x & 7)];
    int ix[K];
    #pragma unroll
    for (int k = 0; k < K; ++k) ix[k] = __builtin_amdgcn_readlane(myix, k);

    // Column positions: 4 y * 8 k = 32 contiguous ints = 8x int4 (per-lane).
    int jv[4 * K];
    {
        const int4* pp = (const int4*)(posT + (size_t)y0 * K);
        #pragma unroll
        for (int q = 0; q < 8; ++q) {
            int4 v = pp[q];
            jv[4 * q + 0] = v.x; jv[4 * q + 1] = v.y;
            jv[4 * q + 2] = v.z; jv[4 * q + 3] = v.w;
        }
    }

    // Raw gathered values (garbage where absent -> masked in the stats pass).
    float vraw[4][K];
    #pragma unroll
    for (int yy = 0; yy < 4; ++yy)
        #pragma unroll
        for (int k = 0; k < K; ++k) vraw[yy][k] = 0.f;

    int mb[4] = {0, 0, 0, 0};

    // LOAD PHASE: no consumers of loaded data -> no vmcnt waits between the
    // present-k groups; all gathers go out back-to-back (max MLP).
    #pragma unroll
    for (int k = 0; k < K; ++k) {
        if (ix[k] >= 0) {                                        // scalar branch
            const float* __restrict__ bk =
                adj + ((size_t)k * NK + (size_t)ix[k]) * NK;
            #pragma unroll
            for (int yy = 0; yy < 4; ++yy) {
                int j  = jv[yy * K + k];
                int jc = j & ~(j >> 31);                          // max(j, 0)
                vraw[yy][k] = bk[jc];                             // unconditional load
                mb[yy] |= (j >= 0) ? (1 << k) : 0;
            }
        }
    }

    // STATS PHASE: exact f32 rounding sequence of the reference (R1-proven).
    float res[4];
    #pragma unroll
    for (int yy = 0; yy < 4; ++yy) {
        const int m = mb[yy];
        float sum = 0.f;
        #pragma unroll
        for (int k = 0; k < K; ++k) {
            bool p = (m >> k) & 1;
            sum += p ? vraw[yy][k] : 0.f;                         // masked, k-ascending
        }
        float cnt  = (float)__popc(m);
        float n    = fmaxf(cnt, 1e-5f);
        float mean = sum / n;                                     // IEEE divide

        float cs = 0.f, vs = 0.f;
        #pragma unroll
        for (int k = 0; k < K; ++k) {
            bool  p = (m >> k) & 1;
            float a = p ? vraw[yy][k] : 0.f;
            cs += (p && (a > TAU_C)) ? 1.f : 0.f;
            float d = a - mean;
            vs += p ? d * d : 0.f;                                // select blocks fma-fuse
        }
        float C = cs / n;
        float V = vs / n;
        float S = C * expf(-V);                                   // precise expf
        float r = (S > TAU_S) ? mean : 0.f;
        res[yy] = (cnt > 0.f) ? r : 0.f;
    }

    float4 o;
    o.x = res[0]; o.y = res[1]; o.z = res[2]; o.w = res[3];
    *(float4*)(out + (size_t)x * N + y0) = o;
}

extern "C" void kernel_launch(void* const* d_in, const int* in_sizes, int n_in,
                              void* d_out, int out_size, void* d_ws, size_t ws_size,
                              hipStream_t stream) {
    const float* adj  = (const float*)d_in[0];   // (K, NK, NK) f32
    const int*   idx  = (const int*)d_in[1];     // (K, NK) i32
    float*       out  = (float*)d_out;           // (N, N) f32
    int*         posT = (int*)d_ws;              // N*K ints = 64 KB

    {
        int total = N * K;                       // 16384
        int block = 256;
        int grid  = (total + block - 1) / block;
        fia_build_pos<<<grid, block, 0, stream>>>(idx, posT);
    }
    {
        dim3 block(256, 1, 1);
        dim3 grid(N / (256 * 4), N, 1);          // 2 x 2048 blocks
        fia_main<<<grid, block, 0, stream>>>(adj, posT, out);
    }
}

// Round 5
// 39.367 us; speedup vs baseline: 1.1384x; 1.0878x over previous
//
#include <hip/hip_runtime.h>

#define N  2048
#define K  8
#define NK 1024
#define TAU_C 0.5f
#define TAU_S 0.5f

// posT[x*K + k] = position of node x in client k's sorted index list, or -1.
// One thread per (x,k) cell; binary search => every cell written exactly once,
// no memset / init pass needed (graph contains only kernel nodes).
__global__ void fia_build_pos(const int* __restrict__ idx, int* __restrict__ posT) {
    int t = blockIdx.x * blockDim.x + threadIdx.x;   // t = x*K + k
    if (t < N * K) {
        int x = t >> 3;         // t / K
        int k = t & 7;          // t % K
        const int* a = idx + k * NK;                 // sorted, 1024 ints (L2-hot)
        int lo = 0, hi = NK;                         // search [lo, hi)
        #pragma unroll 1
        while (lo < hi) {
            int mid = (lo + hi) >> 1;
            if (a[mid] < x) lo = mid + 1; else hi = mid;
        }
        int p = (lo < NK && a[lo] == x) ? lo : -1;
        posT[t] = p;                                 // fully coalesced write
    }
}

// One block per output row x. Present clients' adj rows (<= 8 x 4KB) are staged
// into LDS with coalesced float2 loads; the scattered gathers then hit LDS
// instead of the L1/TA path. 512 threads x 4 consecutive y each.
__global__ void __launch_bounds__(512)
fia_main(const float* __restrict__ adj,
         const int* __restrict__ posT,
         float* __restrict__ out) {
    __shared__ float lds[K * NK];                    // 32 KB

    const int x   = blockIdx.x;                      // row (block-uniform)
    const int tid = threadIdx.x;
    const int y0  = tid * 4;                         // 4 consecutive columns

    // Row positions: lane-varying vector load + readlane -> uniform SGPRs
    // (guaranteed global_load; dodges the R2 graph-replay s_load staleness).
    int myix = posT[(size_t)x * K + (tid & 7)];
    int ix[K];
    #pragma unroll
    for (int k = 0; k < K; ++k) ix[k] = __builtin_amdgcn_readlane(myix, k);

    // STAGE: issue all global loads first (max MLP), then all LDS writes.
    // 512 threads x float2 = 1024 floats = one adj row per present k.
    float2 stg[K];
    #pragma unroll
    for (int k = 0; k < K; ++k) {
        if (ix[k] >= 0) {                            // uniform scalar branch
            const float2* __restrict__ src =
                (const float2*)(adj + ((size_t)k * NK + (size_t)ix[k]) * NK);
            stg[k] = src[tid];                       // fully coalesced
        }
    }
    #pragma unroll
    for (int k = 0; k < K; ++k) {
        if (ix[k] >= 0) {
            ((float2*)(lds + k * NK))[tid] = stg[k];
        }
    }
    __syncthreads();

    // Column positions: 4 y * 8 k = 32 contiguous ints = 8x int4 per thread.
    int jv[4 * K];
    {
        const int4* pp = (const int4*)(posT + (size_t)y0 * K);
        #pragma unroll
        for (int q = 0; q < 8; ++q) {
            int4 v = pp[q];
            jv[4 * q + 0] = v.x; jv[4 * q + 1] = v.y;
            jv[4 * q + 2] = v.z; jv[4 * q + 3] = v.w;
        }
    }

    // GATHER from LDS (garbage where absent -> masked in stats).
    float vraw[4][K];
    #pragma unroll
    for (int yy = 0; yy < 4; ++yy)
        #pragma unroll
        for (int k = 0; k < K; ++k) vraw[yy][k] = 0.f;

    int mb[4] = {0, 0, 0, 0};

    #pragma unroll
    for (int k = 0; k < K; ++k) {
        if (ix[k] >= 0) {                            // uniform scalar branch
            #pragma unroll
            for (int yy = 0; yy < 4; ++yy) {
                int j  = jv[yy * K + k];
                int jc = j & ~(j >> 31);             // max(j, 0)
                vraw[yy][k] = lds[k * NK + jc];      // ds_read_b32
                mb[yy] |= (j >= 0) ? (1 << k) : 0;
            }
        }
    }

    // STATS: exact f32 rounding sequence of the reference (R1/R4-proven).
    float res[4];
    #pragma unroll
    for (int yy = 0; yy < 4; ++yy) {
        const int m = mb[yy];
        float sum = 0.f;
        #pragma unroll
        for (int k = 0; k < K; ++k) {
            bool p = (m >> k) & 1;
            sum += p ? vraw[yy][k] : 0.f;            // masked, k-ascending
        }
        float cnt  = (float)__popc(m);
        float n    = fmaxf(cnt, 1e-5f);
        float mean = sum / n;                        // IEEE divide

        float cs = 0.f, vs = 0.f;
        #pragma unroll
        for (int k = 0; k < K; ++k) {
            bool  p = (m >> k) & 1;
            float a = p ? vraw[yy][k] : 0.f;
            cs += (p && (a > TAU_C)) ? 1.f : 0.f;
            float d = a - mean;
            vs += p ? d * d : 0.f;                   // select blocks fma-fuse
        }
        float C = cs / n;
        float V = vs / n;
        float S = C * expf(-V);                      // precise expf
        float r = (S > TAU_S) ? mean : 0.f;
        res[yy] = (cnt > 0.f) ? r : 0.f;
    }

    float4 o;
    o.x = res[0]; o.y = res[1]; o.z = res[2]; o.w = res[3];
    *(float4*)(out + (size_t)x * N + y0) = o;
}

extern "C" void kernel_launch(void* const* d_in, const int* in_sizes, int n_in,
                              void* d_out, int out_size, void* d_ws, size_t ws_size,
                              hipStream_t stream) {
    const float* adj  = (const float*)d_in[0];   // (K, NK, NK) f32
    const int*   idx  = (const int*)d_in[1];     // (K, NK) i32
    float*       out  = (float*)d_out;           // (N, N) f32
    int*         posT = (int*)d_ws;              // N*K ints = 64 KB

    {
        int total = N * K;                       // 16384
        int block = 256;
        int grid  = (total + block - 1) / block;
        fia_build_pos<<<grid, block, 0, stream>>>(idx, posT);
    }
    {
        dim3 block(512, 1, 1);
        dim3 grid(N, 1, 1);                      // one block per output row
        fia_main<<<grid, block, 0, stream>>>(adj, posT, out);
    }
}